// Round 13
// baseline (995.330 us; speedup 1.0000x reference)
//
#include <hip/hip_runtime.h>
#include <hip/hip_bf16.h>

#define BB 64
#define NN 2048
#define QQ 1024
#define SS 512
#define NCH 16
#define GRID 512

__device__ const int PIDX[36] = {
    0, 2, 5, 8, 12, 17, 22, 27, 32, 38, 45, 52, 59, 66, 73, 80,
    88, 97, 106, 115, 124, 133, 142, 151, 160,
    170, 181, 192, 203, 214, 225, 236, 247, 258, 269, 280};

struct Args {
    const float *x, *dirs, *A_sh, *De0, *De1, *De2, *Dc1, *Dc2, *Dc3;
    const float *W0, *b0, *W1, *b1, *W2, *b2;
    const float *g0, *be0, *g1, *be1, *g2, *be2;
    const float *Wfc1, *bfc1, *gfc1, *befc1, *Wfc2, *bfc2, *gfc2, *befc2, *Wout, *bout;
    float *Dg0t, *rs0, *Det1, *Det2, *pbuf, *yq, *part, *ym, *ht0, *ht1, *ht2, *stats, *out;
    unsigned* bar;
};

// device-scope grid barrier (cooperative-groups style; bar[0]=count, bar[1]=gen)
__device__ __forceinline__ void gbar(unsigned* bar) {
    __syncthreads();
    if (threadIdx.x == 0) {
        __threadfence();  // write back local XCD L2 to coherent point
        unsigned g = __hip_atomic_load(&bar[1], __ATOMIC_RELAXED, __HIP_MEMORY_SCOPE_AGENT);
        unsigned arr = __hip_atomic_fetch_add(&bar[0], 1u, __ATOMIC_ACQ_REL, __HIP_MEMORY_SCOPE_AGENT);
        if (arr == GRID - 1) {
            __hip_atomic_store(&bar[0], 0u, __ATOMIC_RELAXED, __HIP_MEMORY_SCOPE_AGENT);
            __hip_atomic_fetch_add(&bar[1], 1u, __ATOMIC_RELEASE, __HIP_MEMORY_SCOPE_AGENT);
        } else {
            while (__hip_atomic_load(&bar[1], __ATOMIC_RELAXED, __HIP_MEMORY_SCOPE_AGENT) == g)
                __builtin_amdgcn_s_sleep(2);
        }
        (void)__hip_atomic_load(&bar[1], __ATOMIC_ACQUIRE, __HIP_MEMORY_SCOPE_AGENT);  // inv caches
    }
    __syncthreads();
}

// ---------------- coef GEMM unit: 64x64 tile, BN+LReLU fused at staging ----------------
template <int TT, int UU, int QKN>
__device__ __forceinline__ void coef_unit(float* smem, int mt, int nt, int qk, const Args& a,
                                          const float* Dc, const float* stats,
                                          const float* g, const float* be) {
    constexpr int KC = QQ / QKN;
    float* lA = smem;            // [32][68]
    float* lB = smem + 2176;     // [32][68]
    float* lsu = smem + 4352;
    float* ltu = smem + 4352 + UU;
    int tid = threadIdx.x;
    int m0 = mt * 64, n0 = nt * 64, k0 = qk * KC;
    if (tid < UU) {
        const float inv = 1.0f / (BB * QQ);
        float mm = stats[tid] * inv;
        float var = stats[UU + tid] * inv - mm * mm;
        float s = g[tid] * rsqrtf(fmaxf(var, 0.f) + 1e-3f);
        lsu[tid] = s;
        ltu[tid] = be[tid] - mm * s;
    }
    __syncthreads();
    int r = tid >> 2, f = (tid & 3) * 4;
    bool mok = (m0 + r) < TT;
    const float* arow = Dc + (size_t)(mok ? (m0 + r) : 0) * QQ;
    const float* brow = a.yq + (size_t)(n0 + r) * QQ;
    float su = lsu[(n0 + r) % UU], tu = ltu[(n0 + r) % UU];
    int tg = tid >> 4, ug = tid & 15;
    float acc[4][4];
#pragma unroll
    for (int i = 0; i < 4; i++)
#pragma unroll
        for (int j = 0; j < 4; j++) acc[i][j] = 0.f;
    for (int kb = 0; kb < KC; kb += 32) {
        int kg = k0 + kb;
#pragma unroll
        for (int p = 0; p < 2; p++) {
            int ko = f + p * 16;
            float4 a4 = make_float4(0.f, 0.f, 0.f, 0.f);
            if (mok) a4 = *(const float4*)(arow + kg + ko);
            float4 b4 = *(const float4*)(brow + kg + ko);
#pragma unroll
            for (int i = 0; i < 4; i++) {
                float v = fmaf((&b4.x)[i], su, tu);
                lA[(ko + i) * 68 + r] = (&a4.x)[i];
                lB[(ko + i) * 68 + r] = (v > 0.f) ? v : 0.3f * v;
            }
        }
        __syncthreads();
#pragma unroll 2
        for (int kk = 0; kk < 32; kk++) {
            float4 a4 = *(const float4*)&lA[kk * 68 + tg * 4];
            float4 b4 = *(const float4*)&lB[kk * 68 + ug * 4];
#pragma unroll
            for (int i = 0; i < 4; i++) {
                float av = (&a4.x)[i];
                acc[i][0] = fmaf(av, b4.x, acc[i][0]);
                acc[i][1] = fmaf(av, b4.y, acc[i][1]);
                acc[i][2] = fmaf(av, b4.z, acc[i][2]);
                acc[i][3] = fmaf(av, b4.w, acc[i][3]);
            }
        }
        __syncthreads();
    }
    int n = n0 + ug * 4;
    int b = n / UU, u0 = n % UU;
#pragma unroll
    for (int i = 0; i < 4; i++) {
        int t = m0 + tg * 4 + i;
        if (t < TT)
            *(float4*)&a.part[(((size_t)qk * BB + b) * TT + t) * UU + u0] =
                make_float4(acc[i][0], acc[i][1], acc[i][2], acc[i][3]);
    }
}

// ---------------- redmix unit: reduce QKN partials + W-mix + bias -> ym[(b,u)][TTp] ----------------
template <int TT, int CC, int UU, int QKN, int TTp>
__device__ __forceinline__ void redmix_unit(float* smem, int b, const Args& a,
                                            const float* W, const float* bias) {
    constexpr int CCp = CC + 1;
    float* lyt = smem;
    int tid = threadIdx.x;
    for (int i = tid; i < TT * CC; i += 256) {
        float v = 0.f;
#pragma unroll
        for (int k = 0; k < QKN; k++) v += a.part[(size_t)k * (BB * TT * CC) + (size_t)b * TT * CC + i];
        lyt[(i / CC) * CCp + (i % CC)] = v;
    }
    __syncthreads();
    for (int i = tid; i < UU * TTp; i += 256) {
        int u = i / TTp, t = i % TTp;
        float m = 0.f;
        if (t < TT) {
            m = bias[u];
#pragma unroll
            for (int c = 0; c < CC; c++) m = fmaf(lyt[t * CCp + c], W[c * UU + u], m);
        }
        a.ym[((size_t)b * UU + u) * TTp + t] = m;
    }
}

// ---------------- evalG unit: yq[n=(b,u)][q] = sum_t ym[n][t]*Det[t][q], fused stats ----------------
template <int TT, int TTp, int UU>
__device__ __forceinline__ void evalG_unit(float* smem, int mt, int qt, const Args& a,
                                           const float* Det, float* stats) {
    float* lA = smem;
    float* lB = smem + 2176;
    float* sred = smem + 4352;  // [2][64]
    int tid = threadIdx.x;
    int m0 = mt * 64, q0 = qt * 64;
    int r = tid >> 2, f = (tid & 3) * 4;
    const float* arow = a.ym + (size_t)(m0 + r) * TTp;
    int br = tid >> 4, bq = (tid & 15) * 4;
    int tg = tid >> 4, ug = tid & 15;
    float acc[4][4];
#pragma unroll
    for (int i = 0; i < 4; i++)
#pragma unroll
        for (int j = 0; j < 4; j++) acc[i][j] = 0.f;
    for (int kb = 0; kb < TT; kb += 32) {
#pragma unroll
        for (int p = 0; p < 2; p++) {
            int ko = f + p * 16;
            float4 a4 = *(const float4*)(arow + kb + ko);
#pragma unroll
            for (int i = 0; i < 4; i++) lA[(ko + i) * 68 + r] = (&a4.x)[i];
            int kk = br + p * 16;
            int t = kb + kk;
            float4 b4 = make_float4(0.f, 0.f, 0.f, 0.f);
            if (t < TT) b4 = *(const float4*)(Det + (size_t)t * QQ + q0 + bq);
            *(float4*)&lB[kk * 68 + bq] = b4;
        }
        __syncthreads();
#pragma unroll 2
        for (int kk = 0; kk < 32; kk++) {
            float4 a4 = *(const float4*)&lA[kk * 68 + tg * 4];
            float4 b4 = *(const float4*)&lB[kk * 68 + ug * 4];
#pragma unroll
            for (int i = 0; i < 4; i++) {
                float av = (&a4.x)[i];
                acc[i][0] = fmaf(av, b4.x, acc[i][0]);
                acc[i][1] = fmaf(av, b4.y, acc[i][1]);
                acc[i][2] = fmaf(av, b4.z, acc[i][2]);
                acc[i][3] = fmaf(av, b4.w, acc[i][3]);
            }
        }
        __syncthreads();
    }
    float s1[4], s2[4];
#pragma unroll
    for (int i = 0; i < 4; i++) {
        int m = m0 + tg * 4 + i;
        *(float4*)&a.yq[(size_t)m * QQ + q0 + ug * 4] =
            make_float4(acc[i][0], acc[i][1], acc[i][2], acc[i][3]);
        s1[i] = (acc[i][0] + acc[i][1]) + (acc[i][2] + acc[i][3]);
        s2[i] = fmaf(acc[i][0], acc[i][0], fmaf(acc[i][1], acc[i][1],
                 fmaf(acc[i][2], acc[i][2], acc[i][3] * acc[i][3])));
    }
#pragma unroll
    for (int o = 1; o < 16; o <<= 1) {
#pragma unroll
        for (int i = 0; i < 4; i++) {
            s1[i] += __shfl_xor(s1[i], o, 64);
            s2[i] += __shfl_xor(s2[i], o, 64);
        }
    }
    if (ug == 0) {
#pragma unroll
        for (int i = 0; i < 4; i++) {
            sred[tg * 4 + i] = s1[i];
            sred[64 + tg * 4 + i] = s2[i];
        }
    }
    __syncthreads();
    if (tid < 2 * UU) {
        int which = tid / UU, u = tid % UU;
        float s = 0.f;
        for (int rr = u; rr < 64; rr += UU) s += sred[which * 64 + rr];
        atomicAdd(&stats[which * UU + u], s);
    }
}

// ---------------- fc unit: one j, 4-way k-split + batch-BN + relu ----------------
template <int K, int J>
__device__ __forceinline__ void fc_unit(float* smem, int j, const float* in, const float* W,
                                        const float* bias, const float* g, const float* be,
                                        float* out) {
    float* red = smem;  // [4][64]
    int b = threadIdx.x & 63, kq = threadIdx.x >> 6;
    constexpr int KS = K / 4;
    int kbeg = kq * KS;
    float a0 = 0.f, a1 = 0.f, a2 = 0.f, a3 = 0.f;
#pragma unroll 4
    for (int k = kbeg; k < kbeg + KS; k += 4) {
        a0 = fmaf(in[k * BB + b], W[(size_t)k * J + j], a0);
        a1 = fmaf(in[(k + 1) * BB + b], W[(size_t)(k + 1) * J + j], a1);
        a2 = fmaf(in[(k + 2) * BB + b], W[(size_t)(k + 2) * J + j], a2);
        a3 = fmaf(in[(k + 3) * BB + b], W[(size_t)(k + 3) * J + j], a3);
    }
    red[kq * 64 + b] = (a0 + a1) + (a2 + a3);
    __syncthreads();
    if (kq == 0) {
        float acc = red[b] + red[64 + b] + red[128 + b] + red[192 + b] + bias[j];
        float s1 = acc, s2 = acc * acc;
#pragma unroll
        for (int o = 32; o > 0; o >>= 1) {
            s1 += __shfl_xor(s1, o, 64);
            s2 += __shfl_xor(s2, o, 64);
        }
        float m = s1 * (1.0f / 64.f);
        float var = s2 * (1.0f / 64.f) - m * m;
        float sc = g[j] * rsqrtf(fmaxf(var, 0.f) + 1e-3f);
        float v = (acc - m) * sc + be[j];
        out[j * BB + b] = fmaxf(v, 0.f);
    }
}

// ---------------- the megakernel ----------------
__global__ __launch_bounds__(256) void k_mega(Args a) {
    __shared__ __align__(16) float smem[5632];
    const int tid = threadIdx.x;
    const float KL = 18.033688011112042f;  // log2(e)/SIGMA2

    // ===== S0: prep (transposes, gather, rowsum, stats zero) + shells =====
    for (int u = blockIdx.x; u < 1633; u += GRID) {
        int r = tid >> 5, c = tid & 31;
        if (u < 192) {  // De1 -> Det1 [165][1024]
            int tq = u & 31, tt = u >> 5;
            int q0 = tq * 32, t0 = tt * 32;
            for (int rr = r; rr < 32; rr += 8) {
                int t = t0 + c;
                smem[rr * 33 + c] = (t < 165) ? a.De1[(q0 + rr) * 165 + t] : 0.f;
            }
            __syncthreads();
            for (int rr = r; rr < 32; rr += 8) {
                int t = t0 + rr;
                if (t < 165) a.Det1[t * QQ + q0 + c] = smem[c * 33 + rr];
            }
        } else if (u < 288) {  // De2 -> Det2 [84][1024]
            int i = u - 192;
            int tq = i & 31, tt = i >> 5;
            int q0 = tq * 32, t0 = tt * 32;
            for (int rr = r; rr < 32; rr += 8) {
                int t = t0 + c;
                smem[rr * 33 + c] = (t < 84) ? a.De2[(q0 + rr) * 84 + t] : 0.f;
            }
            __syncthreads();
            for (int rr = r; rr < 32; rr += 8) {
                int t = t0 + rr;
                if (t < 84) a.Det2[t * QQ + q0 + c] = smem[c * 33 + rr];
            }
        } else if (u < 352) {  // gather De0[:, PIDX] -> Dg0t [36][1024]
            int i = u - 288;
            int tq = i & 31, tj = i >> 5;
            int q0 = tq * 32, j0 = tj * 32;
            for (int rr = r; rr < 32; rr += 8) {
                int j = j0 + c;
                smem[rr * 33 + c] = (j < 36) ? a.De0[(q0 + rr) * 286 + PIDX[j]] : 0.f;
            }
            __syncthreads();
            for (int rr = r; rr < 32; rr += 8) {
                int j = j0 + rr;
                if (j < 36) a.Dg0t[j * QQ + q0 + c] = smem[c * 33 + rr];
            }
        } else if (u < 608) {  // rowsum of De0: one q per wave
            int w = tid >> 6, lane = tid & 63;
            int q = (u - 352) * 4 + w;
            float s = 0.f;
#pragma unroll
            for (int p = 0; p < 5; p++) {
                int idx = lane + p * 64;
                if (idx < 286) s += a.De0[q * 286 + idx];
            }
#pragma unroll
            for (int o = 32; o > 0; o >>= 1) s += __shfl_xor(s, o, 64);
            if (lane == 0) a.rs0[q] = s;
        } else if (u == 608) {
            if (tid < 224) a.stats[tid] = 0.f;
        } else {  // shells: idx=(b,zc), 3 shells x 2 s-values = 6 exp chains
            int idx = u - 609;
            int b = idx & 63, zc = idx >> 6;
            float4* lx = (float4*)smem;
            const float* xb = a.x + ((size_t)b * NN + zc * (NN / NCH)) * 3;
            for (int n = tid; n < NN / NCH; n += 256) {
                float X = xb[n * 3 + 0], Y = xb[n * 3 + 1], Z = xb[n * 3 + 2];
                lx[n] = make_float4(X, Y, Z, -KL * (X * X + Y * Y + Z * Z));
            }
            __syncthreads();
            float cxs[3][2], cys[3][2], czs[3][2], bas[3][2];
#pragma unroll
            for (int i = 0; i < 3; i++) {
                float rr = (i == 0) ? 0.4f : ((i == 1) ? 0.8f : 1.2f);
#pragma unroll
                for (int h = 0; h < 2; h++) {
                    int s = tid + h * 256;
                    float cx = rr * a.dirs[(i * SS + s) * 3 + 0];
                    float cy = rr * a.dirs[(i * SS + s) * 3 + 1];
                    float cz = rr * a.dirs[(i * SS + s) * 3 + 2];
                    bas[i][h] = -KL * (cx * cx + cy * cy + cz * cz);
                    cxs[i][h] = 2.f * KL * cx;
                    cys[i][h] = 2.f * KL * cy;
                    czs[i][h] = 2.f * KL * cz;
                }
            }
            float acc[3][2];
#pragma unroll
            for (int i = 0; i < 3; i++) { acc[i][0] = 0.f; acc[i][1] = 0.f; }
#pragma unroll 4
            for (int n = 0; n < NN / NCH; n++) {
                float4 p = lx[n];
#pragma unroll
                for (int i = 0; i < 3; i++)
#pragma unroll
                    for (int h = 0; h < 2; h++)
                        acc[i][h] += __builtin_amdgcn_exp2f(
                            fmaf(cxs[i][h], p.x,
                                 fmaf(cys[i][h], p.y, fmaf(czs[i][h], p.z, p.w + bas[i][h]))));
            }
#pragma unroll
            for (int i = 0; i < 3; i++) {
                float* o = a.pbuf + ((size_t)(zc * 3 + i) * BB + b) * SS;
                o[tid] = acc[i][0];
                o[tid + 256] = acc[i][1];
            }
        }
        __syncthreads();
    }
    gbar(a.bar);

    // ===== S1: eval0 (chunk reduce + SH proj + W0 mix + sparse Wigner eval + stats) =====
    for (int u = blockIdx.x; u < 256; u += GRID) {
        int qc = u & 3, b = u >> 2;
        float* lf = smem;           // [3][512]
        float* lsh = smem + 1536;   // [36][3]
        float* llm = smem + 1648;   // [576]
        float* lred = smem + 2240;  // [4][32]
        for (int i = tid; i < 3 * SS; i += 256) {
            int c = i / SS, s = i % SS;
            float v = 0.f;
#pragma unroll
            for (int zc = 0; zc < NCH; zc++) v += a.pbuf[((size_t)(zc * 3 + c) * BB + b) * SS + s];
            lf[c * SS + s] = v * (1.0f / NN);
        }
        __syncthreads();
        int w = tid >> 6, lane = tid & 63;
        for (int p = w; p < 108; p += 4) {
            int j = p / 3, c = p % 3;
            const float* As = a.A_sh + j * SS;
            float aa = 0.f;
#pragma unroll
            for (int k = 0; k < 8; k++) aa = fmaf(lf[c * SS + lane + 64 * k], As[lane + 64 * k], aa);
#pragma unroll
            for (int o = 32; o > 0; o >>= 1) aa += __shfl_xor(aa, o, 64);
            if (lane == 0) lsh[j * 3 + c] = aa;
        }
        __syncthreads();
        for (int i = tid; i < 576; i += 256) {
            int j = i >> 4, uu = i & 15;
            float m = 0.f;
#pragma unroll
            for (int c = 0; c < 3; c++) m = fmaf(lsh[j * 3 + c], a.W0[c * 16 + uu], m);
            llm[i] = m;
        }
        __syncthreads();
        int q = qc * 256 + tid;
        float acc[16];
#pragma unroll
        for (int uu = 0; uu < 16; uu++) acc[uu] = 0.f;
#pragma unroll 4
        for (int j = 0; j < 36; j++) {
            float d = a.Dg0t[j * QQ + q];
#pragma unroll
            for (int uu = 0; uu < 16; uu++) acc[uu] = fmaf(d, llm[j * 16 + uu], acc[uu]);
        }
        float rb = a.rs0[q];
#pragma unroll
        for (int uu = 0; uu < 16; uu++) acc[uu] = fmaf(a.b0[uu], rb, acc[uu]);
#pragma unroll
        for (int uu = 0; uu < 16; uu++) a.yq[((size_t)b * 16 + uu) * QQ + q] = acc[uu];
#pragma unroll
        for (int uu = 0; uu < 16; uu++) {
            float v = acc[uu], v2 = acc[uu] * acc[uu];
#pragma unroll
            for (int o = 32; o > 0; o >>= 1) {
                v += __shfl_xor(v, o, 64);
                v2 += __shfl_xor(v2, o, 64);
            }
            if (lane == 0) { lred[w * 32 + uu] = v; lred[w * 32 + 16 + uu] = v2; }
        }
        __syncthreads();
        if (tid < 32)
            atomicAdd(&a.stats[tid], lred[tid] + lred[32 + tid] + lred[64 + tid] + lred[96 + tid]);
        __syncthreads();
    }
    gbar(a.bar);

    // ===== S2: coef1 =====
    for (int u = blockIdx.x; u < 384; u += GRID) {
        int mt = u / 128, rem = u % 128;
        coef_unit<165, 16, 8>(smem, mt, rem / 8, rem % 8, a, a.Dc1, a.stats, a.g0, a.be0);
        __syncthreads();
    }
    gbar(a.bar);

    // ===== S3: redmix1 =====
    for (int u = blockIdx.x; u < 64; u += GRID) {
        redmix_unit<165, 16, 32, 8, 192>(smem, u, a, a.W1, a.b1);
        __syncthreads();
    }
    gbar(a.bar);

    // ===== S4: evalG1 =====
    for (int u = blockIdx.x; u < 512; u += GRID) {
        evalG_unit<165, 192, 32>(smem, u & 31, u >> 5, a, a.Det1, a.stats + 32);
        __syncthreads();
    }
    gbar(a.bar);

    // ===== S5: coef2 =====
    for (int u = blockIdx.x; u < 512; u += GRID) {
        int mt = u / 256, rem = u % 256;
        coef_unit<84, 32, 8>(smem, mt, rem / 8, rem % 8, a, a.Dc2, a.stats + 32, a.g1, a.be1);
        __syncthreads();
    }
    gbar(a.bar);

    // ===== S6: redmix2 =====
    for (int u = blockIdx.x; u < 64; u += GRID) {
        redmix_unit<84, 32, 64, 8, 96>(smem, u, a, a.W2, a.b2);
        __syncthreads();
    }
    gbar(a.bar);

    // ===== S7: evalG2 =====
    for (int u = blockIdx.x; u < 1024; u += GRID) {
        evalG_unit<84, 96, 64>(smem, u & 63, u >> 6, a, a.Det2, a.stats + 96);
        __syncthreads();
    }
    gbar(a.bar);

    // ===== S8: coef3 =====
    for (int u = blockIdx.x; u < 512; u += GRID) {
        int mt = u / 256, rem = u % 256;
        coef_unit<84, 64, 4>(smem, mt, rem / 4, rem % 4, a, a.Dc3, a.stats + 96, a.g2, a.be2);
        __syncthreads();
    }
    gbar(a.bar);

    // ===== S9: norms =====
    for (int u = blockIdx.x; u < 64; u += GRID) {
        int b = u;
        float* ly = smem;  // 84*64 = 5376
        for (int i = tid; i < 84 * 64; i += 256) {
            float v = 0.f;
#pragma unroll
            for (int k = 0; k < 4; k++) v += a.part[(size_t)k * (BB * 84 * 64) + b * (84 * 64) + i];
            ly[i] = v;
        }
        __syncthreads();
        int blk = tid >> 6, uu = tid & 63;
        const int offs[4] = {0, 1, 10, 35};
        const int ends[4] = {1, 10, 35, 84};
        float aa = 0.f;
        for (int t = offs[blk]; t < ends[blk]; t++) {
            float v = ly[t * 64 + uu];
            aa = fmaf(v, v, aa);
        }
        a.ht0[(blk * 64 + uu) * BB + b] = sqrtf(fmaxf(aa, 0.f));
        __syncthreads();
    }
    gbar(a.bar);

    // ===== S10: fc1 =====
    for (int u = blockIdx.x; u < 512; u += GRID) {
        fc_unit<256, 512>(smem, u, a.ht0, a.Wfc1, a.bfc1, a.gfc1, a.befc1, a.ht1);
        __syncthreads();
    }
    gbar(a.bar);

    // ===== S11: fc2 =====
    for (int u = blockIdx.x; u < 256; u += GRID) {
        fc_unit<512, 256>(smem, u, a.ht1, a.Wfc2, a.bfc2, a.gfc2, a.befc2, a.ht2);
        __syncthreads();
    }
    gbar(a.bar);

    // ===== S12: out + softmax (all barriers at full-block level) =====
    for (int u = blockIdx.x; u < 64; u += GRID) {
        int b = u;
        float* red = smem;       // [4][64]
        float* sm = smem + 256;  // [64]
        int o = tid & 63, kq = tid >> 6;
        float a0 = 0.f, a1 = 0.f, a2 = 0.f, a3 = 0.f;
        int kbeg = kq * 64;
        if (o < 40) {
#pragma unroll 4
            for (int k = kbeg; k < kbeg + 64; k += 4) {
                a0 = fmaf(a.ht2[k * BB + b], a.Wout[k * 40 + o], a0);
                a1 = fmaf(a.ht2[(k + 1) * BB + b], a.Wout[(k + 1) * 40 + o], a1);
                a2 = fmaf(a.ht2[(k + 2) * BB + b], a.Wout[(k + 2) * 40 + o], a2);
                a3 = fmaf(a.ht2[(k + 3) * BB + b], a.Wout[(k + 3) * 40 + o], a3);
            }
        }
        red[kq * 64 + o] = (a0 + a1) + (a2 + a3);
        __syncthreads();
        float acc = 0.f;
        if (kq == 0) {
            acc = red[o] + red[64 + o] + red[128 + o] + red[192 + o] + ((o < 40) ? a.bout[o] : 0.f);
            sm[o] = (o < 40) ? acc : -3.0e38f;
        }
        __syncthreads();
        for (int s = 32; s > 0; s >>= 1) {
            if (tid < s) sm[tid] = fmaxf(sm[tid], sm[tid + s]);
            __syncthreads();
        }
        float m = sm[0];
        __syncthreads();
        const float L2E = 1.4426950408889634f;
        float e = 0.f;
        if (kq == 0) {
            e = (o < 40) ? exp2f((acc - m) * L2E) : 0.f;
            sm[o] = e;
        }
        __syncthreads();
        for (int s = 32; s > 0; s >>= 1) {
            if (tid < s) sm[tid] += sm[tid + s];
            __syncthreads();
        }
        if (kq == 0 && o < 40) a.out[b * 40 + o] = e / sm[0];
        __syncthreads();
    }
}

// ---------------- workspace layout (float offsets) ----------------
#define OFF_PBUF 0          // 1572864 (part aliases: 1376256)
#define OFF_DG0T 1572864
#define OFF_RS0 1609728
#define OFF_DET1 1610752
#define OFF_DET2 1779712
#define OFF_YQ 1865728
#define OFF_YM 6060032
#define OFF_HT0 6453248
#define OFF_HT1 6469632
#define OFF_HT2 6502400
#define OFF_STATS 6518784
#define OFF_BAR 6519040

extern "C" void kernel_launch(void* const* d_in, const int* in_sizes, int n_in,
                              void* d_out, int out_size, void* d_ws, size_t ws_size,
                              hipStream_t stream) {
    float* ws = (float*)d_ws;
    Args a;
    a.x = (const float*)d_in[0];
    a.dirs = (const float*)d_in[1];
    a.A_sh = (const float*)d_in[2];
    a.De0 = (const float*)d_in[3];
    a.De1 = (const float*)d_in[4];
    a.De2 = (const float*)d_in[5];
    a.Dc1 = (const float*)d_in[6];
    a.Dc2 = (const float*)d_in[7];
    a.Dc3 = (const float*)d_in[8];
    a.W0 = (const float*)d_in[9];
    a.b0 = (const float*)d_in[10];
    a.W1 = (const float*)d_in[11];
    a.b1 = (const float*)d_in[12];
    a.W2 = (const float*)d_in[13];
    a.b2 = (const float*)d_in[14];
    a.g0 = (const float*)d_in[15];
    a.be0 = (const float*)d_in[16];
    a.g1 = (const float*)d_in[17];
    a.be1 = (const float*)d_in[18];
    a.g2 = (const float*)d_in[19];
    a.be2 = (const float*)d_in[20];
    a.Wfc1 = (const float*)d_in[21];
    a.bfc1 = (const float*)d_in[22];
    a.gfc1 = (const float*)d_in[23];
    a.befc1 = (const float*)d_in[24];
    a.Wfc2 = (const float*)d_in[25];
    a.bfc2 = (const float*)d_in[26];
    a.gfc2 = (const float*)d_in[27];
    a.befc2 = (const float*)d_in[28];
    a.Wout = (const float*)d_in[29];
    a.bout = (const float*)d_in[30];
    a.Dg0t = ws + OFF_DG0T;
    a.rs0 = ws + OFF_RS0;
    a.Det1 = ws + OFF_DET1;
    a.Det2 = ws + OFF_DET2;
    a.pbuf = ws + OFF_PBUF;
    a.yq = ws + OFF_YQ;
    a.part = ws + OFF_PBUF;  // alias, disjoint lifetime
    a.ym = ws + OFF_YM;
    a.ht0 = ws + OFF_HT0;
    a.ht1 = ws + OFF_HT1;
    a.ht2 = ws + OFF_HT2;
    a.stats = ws + OFF_STATS;
    a.out = (float*)d_out;
    a.bar = (unsigned*)(ws + OFF_BAR);

    hipMemsetAsync(ws + OFF_BAR, 0, 2 * sizeof(unsigned), stream);
    k_mega<<<GRID, 256, 0, stream>>>(a);
}

// Round 14
// 331.190 us; speedup vs baseline: 3.0053x; 3.0053x over previous
//
#include <hip/hip_runtime.h>
#include <hip/hip_bf16.h>

#define BB 64
#define NN 2048
#define QQ 1024
#define SS 512
#define NCH 16
#define PREPB 609
#define QKN3 4

__device__ const int PIDX[36] = {
    0, 2, 5, 8, 12, 17, 22, 27, 32, 38, 45, 52, 59, 66, 73, 80,
    88, 97, 106, 115, 124, 133, 142, 151, 160,
    170, 181, 192, 203, 214, 225, 236, 247, 258, 269, 280};

// ---------------- merged prep + shells (3 shells x 2 s x 2 n-chains = 12 exp chains/thread) ----------------
__global__ __launch_bounds__(256) void k_preshell(
    const float* __restrict__ De0, const float* __restrict__ De1, const float* __restrict__ De2,
    float* __restrict__ Dg0t, float* __restrict__ rs0,
    float* __restrict__ Det1, float* __restrict__ Det2,
    float* __restrict__ stats,
    const float* __restrict__ x, const float* __restrict__ dirs, float* __restrict__ pbuf) {
    __shared__ float tile[32][33];
    __shared__ float4 lx[NN / NCH];
    int blk = blockIdx.x, tid = threadIdx.x;
    if (blk < PREPB) {
        int r = tid >> 5, c = tid & 31;
        if (blk < 192) {  // De1 -> Det1 [165][1024]
            int tq = blk & 31, tt = blk >> 5;
            int q0 = tq * 32, t0 = tt * 32;
            for (int rr = r; rr < 32; rr += 8) {
                int t = t0 + c;
                tile[rr][c] = (t < 165) ? De1[(q0 + rr) * 165 + t] : 0.f;
            }
            __syncthreads();
            for (int rr = r; rr < 32; rr += 8) {
                int t = t0 + rr;
                if (t < 165) Det1[t * QQ + q0 + c] = tile[c][rr];
            }
        } else if (blk < 288) {  // De2 -> Det2 [84][1024]
            int i = blk - 192;
            int tq = i & 31, tt = i >> 5;
            int q0 = tq * 32, t0 = tt * 32;
            for (int rr = r; rr < 32; rr += 8) {
                int t = t0 + c;
                tile[rr][c] = (t < 84) ? De2[(q0 + rr) * 84 + t] : 0.f;
            }
            __syncthreads();
            for (int rr = r; rr < 32; rr += 8) {
                int t = t0 + rr;
                if (t < 84) Det2[t * QQ + q0 + c] = tile[c][rr];
            }
        } else if (blk < 352) {  // gather De0[:, PIDX] -> Dg0t [36][1024]
            int i = blk - 288;
            int tq = i & 31, tj = i >> 5;
            int q0 = tq * 32, j0 = tj * 32;
            for (int rr = r; rr < 32; rr += 8) {
                int j = j0 + c;
                tile[rr][c] = (j < 36) ? De0[(q0 + rr) * 286 + PIDX[j]] : 0.f;
            }
            __syncthreads();
            for (int rr = r; rr < 32; rr += 8) {
                int j = j0 + rr;
                if (j < 36) Dg0t[j * QQ + q0 + c] = tile[c][rr];
            }
        } else if (blk < 608) {  // rowsum: one q per wave
            int w = tid >> 6, lane = tid & 63;
            int q = (blk - 352) * 4 + w;
            float s = 0.f;
#pragma unroll
            for (int p = 0; p < 5; p++) {
                int idx = lane + p * 64;
                if (idx < 286) s += De0[q * 286 + idx];
            }
#pragma unroll
            for (int o = 32; o > 0; o >>= 1) s += __shfl_xor(s, o, 64);
            if (lane == 0) rs0[q] = s;
        } else {
            if (tid < 224) stats[tid] = 0.f;
        }
        return;
    }
    // ---- shells path: block = (b, zc), all 3 shells, 2-way n-unroll ----
    int idx = blk - PREPB;
    int b = idx & 63, zc = idx >> 6;
    const float KL = 18.033688011112042f;  // log2(e)/SIGMA2, SIGMA2=0.08
    const float* xb = x + ((size_t)b * NN + zc * (NN / NCH)) * 3;
    for (int n = tid; n < NN / NCH; n += 256) {
        float X = xb[n * 3 + 0];
        float Y = xb[n * 3 + 1];
        float Z = xb[n * 3 + 2];
        lx[n] = make_float4(X, Y, Z, -KL * (X * X + Y * Y + Z * Z));
    }
    __syncthreads();
    float cxs[3][2], cys[3][2], czs[3][2], bas[3][2];
#pragma unroll
    for (int i = 0; i < 3; i++) {
        float r = (i == 0) ? 0.4f : ((i == 1) ? 0.8f : 1.2f);
#pragma unroll
        for (int h = 0; h < 2; h++) {
            int s = tid + h * 256;
            float cx = r * dirs[(i * SS + s) * 3 + 0];
            float cy = r * dirs[(i * SS + s) * 3 + 1];
            float cz = r * dirs[(i * SS + s) * 3 + 2];
            bas[i][h] = -KL * (cx * cx + cy * cy + cz * cz);
            cxs[i][h] = 2.f * KL * cx;
            cys[i][h] = 2.f * KL * cy;
            czs[i][h] = 2.f * KL * cz;
        }
    }
    float acc[3][2][2];
#pragma unroll
    for (int i = 0; i < 3; i++)
#pragma unroll
        for (int h = 0; h < 2; h++) { acc[i][h][0] = 0.f; acc[i][h][1] = 0.f; }
#pragma unroll 2
    for (int n = 0; n < NN / NCH; n += 2) {
        float4 p0 = lx[n];
        float4 p1 = lx[n + 1];
#pragma unroll
        for (int i = 0; i < 3; i++)
#pragma unroll
            for (int h = 0; h < 2; h++) {
                acc[i][h][0] += __builtin_amdgcn_exp2f(
                    fmaf(cxs[i][h], p0.x, fmaf(cys[i][h], p0.y, fmaf(czs[i][h], p0.z, p0.w + bas[i][h]))));
                acc[i][h][1] += __builtin_amdgcn_exp2f(
                    fmaf(cxs[i][h], p1.x, fmaf(cys[i][h], p1.y, fmaf(czs[i][h], p1.z, p1.w + bas[i][h]))));
            }
    }
#pragma unroll
    for (int i = 0; i < 3; i++) {
        float* o = pbuf + ((size_t)(zc * 3 + i) * BB + b) * SS;
        o[tid] = acc[i][0][0] + acc[i][0][1];
        o[tid + 256] = acc[i][1][0] + acc[i][1][1];
    }
}

// ---------------- eval0: chunk reduce + SH projection + W0 mix + Wigner eval + stats ----------------
__global__ __launch_bounds__(256) void k_eval0(const float* __restrict__ pbuf,
                                               const float* __restrict__ A_sh,
                                               const float* __restrict__ W0,
                                               const float* __restrict__ b0,
                                               const float* __restrict__ Dg0t,
                                               const float* __restrict__ rs0,
                                               float* __restrict__ yq, float* __restrict__ stats) {
    __shared__ float lf[3][SS];
    __shared__ float lsh[36][3];
    __shared__ float llm[576];
    __shared__ float lred[4][32];
    int qc = blockIdx.x, b = blockIdx.y, tid = threadIdx.x;
    for (int i = tid; i < 3 * SS; i += 256) {
        int c = i / SS, s = i % SS;
        float v = 0.f;
#pragma unroll
        for (int zc = 0; zc < NCH; zc++) v += pbuf[((size_t)(zc * 3 + c) * BB + b) * SS + s];
        lf[c][s] = v * (1.0f / NN);
    }
    __syncthreads();
    int w = tid >> 6, lane = tid & 63;
    for (int p = w; p < 108; p += 4) {
        int j = p / 3, c = p % 3;
        const float* As = A_sh + j * SS;
        float a = 0.f;
#pragma unroll
        for (int k = 0; k < 8; k++) a = fmaf(lf[c][lane + 64 * k], As[lane + 64 * k], a);
#pragma unroll
        for (int o = 32; o > 0; o >>= 1) a += __shfl_xor(a, o, 64);
        if (lane == 0) lsh[j][c] = a;
    }
    __syncthreads();
    for (int i = tid; i < 576; i += 256) {
        int j = i >> 4, u = i & 15;
        float m = 0.f;
#pragma unroll
        for (int c = 0; c < 3; c++) m = fmaf(lsh[j][c], W0[c * 16 + u], m);
        llm[i] = m;
    }
    __syncthreads();
    int q = qc * 256 + tid;
    float acc[16];
#pragma unroll
    for (int u = 0; u < 16; u++) acc[u] = 0.f;
#pragma unroll 4
    for (int j = 0; j < 36; j++) {
        float d = Dg0t[j * QQ + q];
#pragma unroll
        for (int u = 0; u < 16; u++) acc[u] = fmaf(d, llm[j * 16 + u], acc[u]);
    }
    float rb = rs0[q];
#pragma unroll
    for (int u = 0; u < 16; u++) acc[u] = fmaf(b0[u], rb, acc[u]);
#pragma unroll
    for (int u = 0; u < 16; u++) yq[((size_t)b * 16 + u) * QQ + q] = acc[u];
#pragma unroll
    for (int u = 0; u < 16; u++) {
        float v = acc[u], v2 = acc[u] * acc[u];
#pragma unroll
        for (int o = 32; o > 0; o >>= 1) {
            v += __shfl_xor(v, o, 64);
            v2 += __shfl_xor(v2, o, 64);
        }
        if (lane == 0) { lred[w][u] = v; lred[w][16 + u] = v2; }
    }
    __syncthreads();
    if (tid < 32) atomicAdd(&stats[tid], lred[0][tid] + lred[1][tid] + lred[2][tid] + lred[3][tid]);
}

// ---------------- coef GEMM: float4 staging, float4 partial stores ----------------
template <int TT, int UU, int QKN>
__global__ __launch_bounds__(256) void k_coefG(const float* __restrict__ yq,
                                               const float* __restrict__ Dc,
                                               const float* __restrict__ stats,
                                               const float* __restrict__ g,
                                               const float* __restrict__ be,
                                               float* __restrict__ part) {
    constexpr int KC = QQ / QKN;
    __shared__ float lA[32][68];
    __shared__ float lB[32][68];
    __shared__ float lsu[UU], ltu[UU];
    int mt = blockIdx.x, nt = blockIdx.y, qk = blockIdx.z, tid = threadIdx.x;
    int m0 = mt * 64, n0 = nt * 64, k0 = qk * KC;
    if (tid < UU) {
        const float inv = 1.0f / (BB * QQ);
        float mm = stats[tid] * inv;
        float var = stats[UU + tid] * inv - mm * mm;
        float s = g[tid] * rsqrtf(fmaxf(var, 0.f) + 1e-3f);
        lsu[tid] = s;
        ltu[tid] = be[tid] - mm * s;
    }
    __syncthreads();
    int r = tid >> 2, f = (tid & 3) * 4;
    bool mok = (m0 + r) < TT;
    const float* arow = Dc + (size_t)(mok ? (m0 + r) : 0) * QQ;
    const float* brow = yq + (size_t)(n0 + r) * QQ;
    float su = lsu[(n0 + r) % UU], tu = ltu[(n0 + r) % UU];
    int tg = tid >> 4, ug = tid & 15;
    float acc[4][4];
#pragma unroll
    for (int i = 0; i < 4; i++)
#pragma unroll
        for (int j = 0; j < 4; j++) acc[i][j] = 0.f;
    for (int kb = 0; kb < KC; kb += 32) {
        int kg = k0 + kb;
#pragma unroll
        for (int p = 0; p < 2; p++) {
            int ko = f + p * 16;
            float4 a4 = make_float4(0.f, 0.f, 0.f, 0.f);
            if (mok) a4 = *(const float4*)(arow + kg + ko);
            float4 b4 = *(const float4*)(brow + kg + ko);
#pragma unroll
            for (int i = 0; i < 4; i++) {
                float v = fmaf((&b4.x)[i], su, tu);
                lA[ko + i][r] = (&a4.x)[i];
                lB[ko + i][r] = (v > 0.f) ? v : 0.3f * v;
            }
        }
        __syncthreads();
#pragma unroll 2
        for (int kk = 0; kk < 32; kk++) {
            float4 a4 = *(const float4*)&lA[kk][tg * 4];
            float4 b4 = *(const float4*)&lB[kk][ug * 4];
#pragma unroll
            for (int i = 0; i < 4; i++) {
                float av = (&a4.x)[i];
                acc[i][0] = fmaf(av, b4.x, acc[i][0]);
                acc[i][1] = fmaf(av, b4.y, acc[i][1]);
                acc[i][2] = fmaf(av, b4.z, acc[i][2]);
                acc[i][3] = fmaf(av, b4.w, acc[i][3]);
            }
        }
        __syncthreads();
    }
    int n = n0 + ug * 4;
    int b = n / UU, u0 = n % UU;
#pragma unroll
    for (int i = 0; i < 4; i++) {
        int t = m0 + tg * 4 + i;
        if (t < TT)
            *(float4*)&part[(((size_t)qk * BB + b) * TT + t) * UU + u0] =
                make_float4(acc[i][0], acc[i][1], acc[i][2], acc[i][3]);
    }
}

// ---------------- redmix: grid (b, t-slice) = 512 blocks; reduce QKN partials + W-mix ----------------
template <int TT, int CC, int UU, int QKN, int TTp, int TS>
__global__ __launch_bounds__(256) void k_redmix(const float* __restrict__ part,
                                                const float* __restrict__ W,
                                                const float* __restrict__ bias,
                                                float* __restrict__ ym) {
    constexpr int TSL = TTp / TS;
    __shared__ float lyt[TSL][CC + 1];
    int b = blockIdx.x, ts = blockIdx.y, tid = threadIdx.x;
    int t0 = ts * TSL;
    for (int i = tid; i < TSL * CC; i += 256) {
        int tl = i / CC, c = i % CC;
        int t = t0 + tl;
        float v = 0.f;
        if (t < TT) {
#pragma unroll
            for (int k = 0; k < QKN; k++)
                v += part[(size_t)k * (BB * TT * CC) + ((size_t)b * TT + t) * CC + c];
        }
        lyt[tl][c] = v;
    }
    __syncthreads();
    for (int i = tid; i < UU * TSL; i += 256) {
        int u = i / TSL, tl = i % TSL;
        int t = t0 + tl;
        float m = 0.f;
        if (t < TT) {
            m = bias[u];
#pragma unroll
            for (int c = 0; c < CC; c++) m = fmaf(lyt[tl][c], W[c * UU + u], m);
        }
        ym[((size_t)b * UU + u) * TTp + t] = m;
    }
}

// ---------------- eval as tiled GEMM: yq[n=(b,u)][q] = sum_t ym[n][t]*Det[t][q], fused stats ----------------
template <int TT, int TTp, int UU>
__global__ __launch_bounds__(256) void k_evalG(const float* __restrict__ ym,
                                               const float* __restrict__ Det,
                                               float* __restrict__ yq,
                                               float* __restrict__ stats) {
    __shared__ float lA[32][68];
    __shared__ float lB[32][68];
    __shared__ float sred[2][64];
    int mt = blockIdx.x, qt = blockIdx.y, tid = threadIdx.x;
    int m0 = mt * 64, q0 = qt * 64;
    int r = tid >> 2, f = (tid & 3) * 4;
    const float* arow = ym + (size_t)(m0 + r) * TTp;
    int br = tid >> 4, bq = (tid & 15) * 4;
    int tg = tid >> 4, ug = tid & 15;
    float acc[4][4];
#pragma unroll
    for (int i = 0; i < 4; i++)
#pragma unroll
        for (int j = 0; j < 4; j++) acc[i][j] = 0.f;
    for (int kb = 0; kb < TT; kb += 32) {
#pragma unroll
        for (int p = 0; p < 2; p++) {
            int ko = f + p * 16;
            float4 a4 = *(const float4*)(arow + kb + ko);
#pragma unroll
            for (int i = 0; i < 4; i++) lA[ko + i][r] = (&a4.x)[i];
            int kk = br + p * 16;
            int t = kb + kk;
            float4 b4 = make_float4(0.f, 0.f, 0.f, 0.f);
            if (t < TT) b4 = *(const float4*)(Det + (size_t)t * QQ + q0 + bq);
            *(float4*)&lB[kk][bq] = b4;
        }
        __syncthreads();
#pragma unroll 2
        for (int kk = 0; kk < 32; kk++) {
            float4 a4 = *(const float4*)&lA[kk][tg * 4];
            float4 b4 = *(const float4*)&lB[kk][ug * 4];
#pragma unroll
            for (int i = 0; i < 4; i++) {
                float av = (&a4.x)[i];
                acc[i][0] = fmaf(av, b4.x, acc[i][0]);
                acc[i][1] = fmaf(av, b4.y, acc[i][1]);
                acc[i][2] = fmaf(av, b4.z, acc[i][2]);
                acc[i][3] = fmaf(av, b4.w, acc[i][3]);
            }
        }
        __syncthreads();
    }
    float s1[4], s2[4];
#pragma unroll
    for (int i = 0; i < 4; i++) {
        int m = m0 + tg * 4 + i;
        *(float4*)&yq[(size_t)m * QQ + q0 + ug * 4] =
            make_float4(acc[i][0], acc[i][1], acc[i][2], acc[i][3]);
        s1[i] = (acc[i][0] + acc[i][1]) + (acc[i][2] + acc[i][3]);
        s2[i] = fmaf(acc[i][0], acc[i][0], fmaf(acc[i][1], acc[i][1],
                 fmaf(acc[i][2], acc[i][2], acc[i][3] * acc[i][3])));
    }
#pragma unroll
    for (int o = 1; o < 16; o <<= 1) {
#pragma unroll
        for (int i = 0; i < 4; i++) {
            s1[i] += __shfl_xor(s1[i], o, 64);
            s2[i] += __shfl_xor(s2[i], o, 64);
        }
    }
    if (ug == 0) {
#pragma unroll
        for (int i = 0; i < 4; i++) {
            sred[0][tg * 4 + i] = s1[i];
            sred[1][tg * 4 + i] = s2[i];
        }
    }
    __syncthreads();
    if (tid < 2 * UU) {
        int which = tid / UU, u = tid % UU;
        float s = 0.f;
        for (int rr = u; rr < 64; rr += UU) s += sred[which][rr];
        atomicAdd(&stats[which * UU + u], s);
    }
}

// ---------------- norms: grid (b, blk), 4-way t-split, partial-reduce inline ----------------
__global__ __launch_bounds__(256) void k_norms(const float* __restrict__ part, float* __restrict__ ht0) {
    __shared__ float red[4][64];
    int b = blockIdx.x, blk = blockIdx.y;
    int tq = threadIdx.x >> 6, u = threadIdx.x & 63;
    const int offs[4] = {0, 1, 10, 35};
    const int ends[4] = {1, 10, 35, 84};
    float a = 0.f;
    for (int t = offs[blk] + tq; t < ends[blk]; t += 4) {
        float v = 0.f;
#pragma unroll
        for (int k = 0; k < QKN3; k++)
            v += part[(size_t)k * (BB * 84 * 64) + (b * 84 + t) * 64 + u];
        a = fmaf(v, v, a);
    }
    red[tq][u] = a;
    __syncthreads();
    if (tq == 0) {
        float s = red[0][u] + red[1][u] + red[2][u] + red[3][u];
        ht0[(blk * 64 + u) * BB + b] = sqrtf(fmaxf(s, 0.f));
    }
}

// ---------------- fc + batch-BN + relu: 8-way k-split, 4-acc unroll ----------------
template <int K, int J>
__global__ __launch_bounds__(512) void k_fc(const float* __restrict__ in, const float* __restrict__ W,
                                            const float* __restrict__ bias, const float* __restrict__ g,
                                            const float* __restrict__ be, float* __restrict__ out) {
    __shared__ float red[8][64];
    int j = blockIdx.x;
    int b = threadIdx.x & 63, kq = threadIdx.x >> 6;
    constexpr int KS = K / 8;
    int kbeg = kq * KS;
    float a0 = 0.f, a1 = 0.f, a2 = 0.f, a3 = 0.f;
#pragma unroll 4
    for (int k = kbeg; k < kbeg + KS; k += 4) {
        a0 = fmaf(in[k * BB + b], W[(size_t)k * J + j], a0);
        a1 = fmaf(in[(k + 1) * BB + b], W[(size_t)(k + 1) * J + j], a1);
        a2 = fmaf(in[(k + 2) * BB + b], W[(size_t)(k + 2) * J + j], a2);
        a3 = fmaf(in[(k + 3) * BB + b], W[(size_t)(k + 3) * J + j], a3);
    }
    red[kq][b] = (a0 + a1) + (a2 + a3);
    __syncthreads();
    if (kq == 0) {
        float acc = bias[j];
#pragma unroll
        for (int i = 0; i < 8; i++) acc += red[i][b];
        float s1 = acc, s2 = acc * acc;
#pragma unroll
        for (int o = 32; o > 0; o >>= 1) {
            s1 += __shfl_xor(s1, o, 64);
            s2 += __shfl_xor(s2, o, 64);
        }
        float m = s1 * (1.0f / 64.f);
        float var = s2 * (1.0f / 64.f) - m * m;
        float sc = g[j] * rsqrtf(fmaxf(var, 0.f) + 1e-3f);
        float v = (acc - m) * sc + be[j];
        out[j * BB + b] = fmaxf(v, 0.f);
    }
}

// ---------------- output layer + softmax ----------------
__global__ __launch_bounds__(256) void k_out(const float* __restrict__ ht2, const float* __restrict__ Wout,
                                             const float* __restrict__ bout, float* __restrict__ outp) {
    __shared__ float red[4][64];
    __shared__ float sm[64];
    int b = blockIdx.x;
    int o = threadIdx.x & 63, kq = threadIdx.x >> 6;
    float a0 = 0.f, a1 = 0.f, a2 = 0.f, a3 = 0.f;
    int kbeg = kq * 64;
    if (o < 40) {
#pragma unroll 4
        for (int k = kbeg; k < kbeg + 64; k += 4) {
            a0 = fmaf(ht2[k * BB + b], Wout[k * 40 + o], a0);
            a1 = fmaf(ht2[(k + 1) * BB + b], Wout[(k + 1) * 40 + o], a1);
            a2 = fmaf(ht2[(k + 2) * BB + b], Wout[(k + 2) * 40 + o], a2);
            a3 = fmaf(ht2[(k + 3) * BB + b], Wout[(k + 3) * 40 + o], a3);
        }
    }
    red[kq][o] = (a0 + a1) + (a2 + a3);
    __syncthreads();
    if (kq == 0) {
        float acc = red[0][o] + red[1][o] + red[2][o] + red[3][o] + ((o < 40) ? bout[o] : 0.f);
        sm[o] = (o < 40) ? acc : -3.0e38f;
        __syncthreads();
        for (int s = 32; s > 0; s >>= 1) {
            if (o < s) sm[o] = fmaxf(sm[o], sm[o + s]);
            __syncthreads();
        }
        float m = sm[0];
        __syncthreads();
        const float L2E = 1.4426950408889634f;
        float e = (o < 40) ? exp2f((acc - m) * L2E) : 0.f;
        sm[o] = e;
        __syncthreads();
        for (int s = 32; s > 0; s >>= 1) {
            if (o < s) sm[o] += sm[o + s];
            __syncthreads();
        }
        if (o < 40) outp[b * 40 + o] = e / sm[0];
    }
}

// ---------------- workspace layout (float offsets) ----------------
// part aliases pbuf (disjoint lifetimes).
#define OFF_PBUF 0          // 1572864 (also part: 1376256)
#define OFF_DG0T 1572864
#define OFF_RS0 1609728
#define OFF_DET1 1610752
#define OFF_DET2 1779712
#define OFF_YQ 1865728
#define OFF_YM 6060032
#define OFF_HT0 6453248
#define OFF_HT1 6469632
#define OFF_HT2 6502400
#define OFF_STATS 6518784

extern "C" void kernel_launch(void* const* d_in, const int* in_sizes, int n_in,
                              void* d_out, int out_size, void* d_ws, size_t ws_size,
                              hipStream_t stream) {
    const float* x = (const float*)d_in[0];
    const float* shell_dirs = (const float*)d_in[1];
    const float* A_sh = (const float*)d_in[2];
    const float* D_eval0 = (const float*)d_in[3];
    const float* D_eval1 = (const float*)d_in[4];
    const float* D_eval2 = (const float*)d_in[5];
    const float* D_coef1 = (const float*)d_in[6];
    const float* D_coef2 = (const float*)d_in[7];
    const float* D_coef_last = (const float*)d_in[8];
    const float* W0 = (const float*)d_in[9];
    const float* b0 = (const float*)d_in[10];
    const float* W1 = (const float*)d_in[11];
    const float* b1 = (const float*)d_in[12];
    const float* W2 = (const float*)d_in[13];
    const float* b2 = (const float*)d_in[14];
    const float* g0 = (const float*)d_in[15];
    const float* be0 = (const float*)d_in[16];
    const float* g1 = (const float*)d_in[17];
    const float* be1 = (const float*)d_in[18];
    const float* g2 = (const float*)d_in[19];
    const float* be2 = (const float*)d_in[20];
    const float* Wfc1 = (const float*)d_in[21];
    const float* bfc1 = (const float*)d_in[22];
    const float* gfc1 = (const float*)d_in[23];
    const float* befc1 = (const float*)d_in[24];
    const float* Wfc2 = (const float*)d_in[25];
    const float* bfc2 = (const float*)d_in[26];
    const float* gfc2 = (const float*)d_in[27];
    const float* befc2 = (const float*)d_in[28];
    const float* Wout = (const float*)d_in[29];
    const float* bout = (const float*)d_in[30];
    float* out = (float*)d_out;

    float* ws = (float*)d_ws;
    float* pbuf = ws + OFF_PBUF;
    float* part = ws + OFF_PBUF;  // alias, disjoint lifetime
    float* Dg0t = ws + OFF_DG0T;
    float* rs0 = ws + OFF_RS0;
    float* Det1 = ws + OFF_DET1;
    float* Det2 = ws + OFF_DET2;
    float* yq = ws + OFF_YQ;
    float* ym = ws + OFF_YM;
    float* ht0 = ws + OFF_HT0;
    float* ht1 = ws + OFF_HT1;
    float* ht2 = ws + OFF_HT2;
    float* stats = ws + OFF_STATS;
    float* stats0 = stats;
    float* stats1 = stats + 32;
    float* stats2 = stats + 96;

    k_preshell<<<PREPB + BB * NCH, 256, 0, stream>>>(
        D_eval0, D_eval1, D_eval2, Dg0t, rs0, Det1, Det2, stats, x, shell_dirs, pbuf);
    k_eval0<<<dim3(4, BB), 256, 0, stream>>>(pbuf, A_sh, W0, b0, Dg0t, rs0, yq, stats0);
    k_coefG<165, 16, 8><<<dim3(3, 16, 8), 256, 0, stream>>>(yq, D_coef1, stats0, g0, be0, part);
    k_redmix<165, 16, 32, 8, 192, 8><<<dim3(BB, 8), 256, 0, stream>>>(part, W1, b1, ym);
    k_evalG<165, 192, 32><<<dim3(32, 16), 256, 0, stream>>>(ym, Det1, yq, stats1);
    k_coefG<84, 32, 8><<<dim3(2, 32, 8), 256, 0, stream>>>(yq, D_coef2, stats1, g1, be1, part);
    k_redmix<84, 32, 64, 8, 96, 8><<<dim3(BB, 8), 256, 0, stream>>>(part, W2, b2, ym);
    k_evalG<84, 96, 64><<<dim3(64, 16), 256, 0, stream>>>(ym, Det2, yq, stats2);
    k_coefG<84, 64, QKN3><<<dim3(2, 64, QKN3), 256, 0, stream>>>(yq, D_coef_last, stats2, g2, be2, part);
    k_norms<<<dim3(BB, 4), 256, 0, stream>>>(part, ht0);
    k_fc<256, 512><<<512, 512, 0, stream>>>(ht0, Wfc1, bfc1, gfc1, befc1, ht1);
    k_fc<512, 256><<<256, 512, 0, stream>>>(ht1, Wfc2, bfc2, gfc2, befc2, ht2);
    k_out<<<BB, 256, 0, stream>>>(ht2, Wout, bout, out);
}

// Round 15
// 312.504 us; speedup vs baseline: 3.1850x; 1.0598x over previous
//
#include <hip/hip_runtime.h>
#include <hip/hip_bf16.h>

#define BB 64
#define NN 2048
#define QQ 1024
#define SS 512
#define NCH 16
#define PREPB 609
#define QKN3 8

__device__ const int PIDX[36] = {
    0, 2, 5, 8, 12, 17, 22, 27, 32, 38, 45, 52, 59, 66, 73, 80,
    88, 97, 106, 115, 124, 133, 142, 151, 160,
    170, 181, 192, 203, 214, 225, 236, 247, 258, 269, 280};

// ---------------- merged prep + shells (3 shells x 2 s = 6 exp chains/thread) ----------------
__global__ __launch_bounds__(256) void k_preshell(
    const float* __restrict__ De0, const float* __restrict__ De1, const float* __restrict__ De2,
    float* __restrict__ Dg0t, float* __restrict__ rs0,
    float* __restrict__ Det1, float* __restrict__ Det2,
    float* __restrict__ stats,
    const float* __restrict__ x, const float* __restrict__ dirs, float* __restrict__ pbuf) {
    __shared__ float tile[32][33];
    __shared__ float4 lx[NN / NCH];
    int blk = blockIdx.x, tid = threadIdx.x;
    if (blk < PREPB) {
        int r = tid >> 5, c = tid & 31;
        if (blk < 192) {  // De1 -> Det1 [165][1024]
            int tq = blk & 31, tt = blk >> 5;
            int q0 = tq * 32, t0 = tt * 32;
            for (int rr = r; rr < 32; rr += 8) {
                int t = t0 + c;
                tile[rr][c] = (t < 165) ? De1[(q0 + rr) * 165 + t] : 0.f;
            }
            __syncthreads();
            for (int rr = r; rr < 32; rr += 8) {
                int t = t0 + rr;
                if (t < 165) Det1[t * QQ + q0 + c] = tile[c][rr];
            }
        } else if (blk < 288) {  // De2 -> Det2 [84][1024]
            int i = blk - 192;
            int tq = i & 31, tt = i >> 5;
            int q0 = tq * 32, t0 = tt * 32;
            for (int rr = r; rr < 32; rr += 8) {
                int t = t0 + c;
                tile[rr][c] = (t < 84) ? De2[(q0 + rr) * 84 + t] : 0.f;
            }
            __syncthreads();
            for (int rr = r; rr < 32; rr += 8) {
                int t = t0 + rr;
                if (t < 84) Det2[t * QQ + q0 + c] = tile[c][rr];
            }
        } else if (blk < 352) {  // gather De0[:, PIDX] -> Dg0t [36][1024]
            int i = blk - 288;
            int tq = i & 31, tj = i >> 5;
            int q0 = tq * 32, j0 = tj * 32;
            for (int rr = r; rr < 32; rr += 8) {
                int j = j0 + c;
                tile[rr][c] = (j < 36) ? De0[(q0 + rr) * 286 + PIDX[j]] : 0.f;
            }
            __syncthreads();
            for (int rr = r; rr < 32; rr += 8) {
                int j = j0 + rr;
                if (j < 36) Dg0t[j * QQ + q0 + c] = tile[c][rr];
            }
        } else if (blk < 608) {  // rowsum: one q per wave
            int w = tid >> 6, lane = tid & 63;
            int q = (blk - 352) * 4 + w;
            float s = 0.f;
#pragma unroll
            for (int p = 0; p < 5; p++) {
                int idx = lane + p * 64;
                if (idx < 286) s += De0[q * 286 + idx];
            }
#pragma unroll
            for (int o = 32; o > 0; o >>= 1) s += __shfl_xor(s, o, 64);
            if (lane == 0) rs0[q] = s;
        } else {
            if (tid < 224) stats[tid] = 0.f;
        }
        return;
    }
    // ---- shells path: block = (b, zc), all 3 shells, 6 chains ----
    int idx = blk - PREPB;
    int b = idx & 63, zc = idx >> 6;
    const float KL = 18.033688011112042f;  // log2(e)/SIGMA2, SIGMA2=0.08
    const float* xb = x + ((size_t)b * NN + zc * (NN / NCH)) * 3;
    for (int n = tid; n < NN / NCH; n += 256) {
        float X = xb[n * 3 + 0];
        float Y = xb[n * 3 + 1];
        float Z = xb[n * 3 + 2];
        lx[n] = make_float4(X, Y, Z, -KL * (X * X + Y * Y + Z * Z));
    }
    __syncthreads();
    float cxs[3][2], cys[3][2], czs[3][2], bas[3][2];
#pragma unroll
    for (int i = 0; i < 3; i++) {
        float r = (i == 0) ? 0.4f : ((i == 1) ? 0.8f : 1.2f);
#pragma unroll
        for (int h = 0; h < 2; h++) {
            int s = tid + h * 256;
            float cx = r * dirs[(i * SS + s) * 3 + 0];
            float cy = r * dirs[(i * SS + s) * 3 + 1];
            float cz = r * dirs[(i * SS + s) * 3 + 2];
            bas[i][h] = -KL * (cx * cx + cy * cy + cz * cz);
            cxs[i][h] = 2.f * KL * cx;
            cys[i][h] = 2.f * KL * cy;
            czs[i][h] = 2.f * KL * cz;
        }
    }
    float acc[3][2];
#pragma unroll
    for (int i = 0; i < 3; i++) { acc[i][0] = 0.f; acc[i][1] = 0.f; }
#pragma unroll 4
    for (int n = 0; n < NN / NCH; n++) {
        float4 p = lx[n];
#pragma unroll
        for (int i = 0; i < 3; i++)
#pragma unroll
            for (int h = 0; h < 2; h++)
                acc[i][h] += __builtin_amdgcn_exp2f(
                    fmaf(cxs[i][h], p.x, fmaf(cys[i][h], p.y, fmaf(czs[i][h], p.z, p.w + bas[i][h]))));
    }
#pragma unroll
    for (int i = 0; i < 3; i++) {
        float* o = pbuf + ((size_t)(zc * 3 + i) * BB + b) * SS;
        o[tid] = acc[i][0];
        o[tid + 256] = acc[i][1];
    }
}

// ---------------- sh: grid (b, c, s-half); chunk reduce + SH half-dots -> lshp[b][36][3][2] ----------------
__global__ __launch_bounds__(256) void k_sh(const float* __restrict__ pbuf,
                                            const float* __restrict__ A_sh,
                                            float* __restrict__ lshp) {
    __shared__ float lf[256];
    int b = blockIdx.x, c = blockIdx.y, h = blockIdx.z, tid = threadIdx.x;
    float v = 0.f;
#pragma unroll
    for (int zc = 0; zc < NCH; zc++)
        v += pbuf[((size_t)(zc * 3 + c) * BB + b) * SS + h * 256 + tid];
    lf[tid] = v * (1.0f / NN);
    __syncthreads();
    int w = tid >> 6, lane = tid & 63;
    for (int j = w; j < 36; j += 4) {
        const float* As = A_sh + j * SS + h * 256;
        float a = 0.f;
#pragma unroll
        for (int k = 0; k < 4; k++) a = fmaf(lf[lane + 64 * k], As[lane + 64 * k], a);
#pragma unroll
        for (int o = 32; o > 0; o >>= 1) a += __shfl_xor(a, o, 64);
        if (lane == 0) lshp[((b * 36 + j) * 3 + c) * 2 + h] = a;
    }
}

// ---------------- eval0: W0 mix + sparse Wigner eval + bias*rowsum + stats ----------------
__global__ __launch_bounds__(256) void k_eval0(const float* __restrict__ lshp,
                                               const float* __restrict__ W0,
                                               const float* __restrict__ b0,
                                               const float* __restrict__ Dg0t,
                                               const float* __restrict__ rs0,
                                               float* __restrict__ yq, float* __restrict__ stats) {
    __shared__ float lsh[36][3];
    __shared__ float llm[576];
    __shared__ float lred[4][32];
    int qc = blockIdx.x, b = blockIdx.y, tid = threadIdx.x;
    if (tid < 108) {
        int j = tid / 3, c = tid % 3;
        lsh[j][c] = lshp[((b * 36 + j) * 3 + c) * 2 + 0] + lshp[((b * 36 + j) * 3 + c) * 2 + 1];
    }
    __syncthreads();
    for (int i = tid; i < 576; i += 256) {
        int j = i >> 4, u = i & 15;
        float m = 0.f;
#pragma unroll
        for (int c = 0; c < 3; c++) m = fmaf(lsh[j][c], W0[c * 16 + u], m);
        llm[i] = m;
    }
    __syncthreads();
    int q = qc * 256 + tid;
    float acc[16];
#pragma unroll
    for (int u = 0; u < 16; u++) acc[u] = 0.f;
#pragma unroll 4
    for (int j = 0; j < 36; j++) {
        float d = Dg0t[j * QQ + q];
#pragma unroll
        for (int u = 0; u < 16; u++) acc[u] = fmaf(d, llm[j * 16 + u], acc[u]);
    }
    float rb = rs0[q];
#pragma unroll
    for (int u = 0; u < 16; u++) acc[u] = fmaf(b0[u], rb, acc[u]);
#pragma unroll
    for (int u = 0; u < 16; u++) yq[((size_t)b * 16 + u) * QQ + q] = acc[u];
    int lane = tid & 63, w = tid >> 6;
#pragma unroll
    for (int u = 0; u < 16; u++) {
        float v = acc[u], v2 = acc[u] * acc[u];
#pragma unroll
        for (int o = 32; o > 0; o >>= 1) {
            v += __shfl_xor(v, o, 64);
            v2 += __shfl_xor(v2, o, 64);
        }
        if (lane == 0) { lred[w][u] = v; lred[w][16 + u] = v2; }
    }
    __syncthreads();
    if (tid < 32) atomicAdd(&stats[tid], lred[0][tid] + lred[1][tid] + lred[2][tid] + lred[3][tid]);
}

// ---------------- coef GEMM: float4 staging, float4 partial stores ----------------
template <int TT, int UU, int QKN>
__global__ __launch_bounds__(256) void k_coefG(const float* __restrict__ yq,
                                               const float* __restrict__ Dc,
                                               const float* __restrict__ stats,
                                               const float* __restrict__ g,
                                               const float* __restrict__ be,
                                               float* __restrict__ part) {
    constexpr int KC = QQ / QKN;
    __shared__ float lA[32][68];
    __shared__ float lB[32][68];
    __shared__ float lsu[UU], ltu[UU];
    int mt = blockIdx.x, nt = blockIdx.y, qk = blockIdx.z, tid = threadIdx.x;
    int m0 = mt * 64, n0 = nt * 64, k0 = qk * KC;
    if (tid < UU) {
        const float inv = 1.0f / (BB * QQ);
        float mm = stats[tid] * inv;
        float var = stats[UU + tid] * inv - mm * mm;
        float s = g[tid] * rsqrtf(fmaxf(var, 0.f) + 1e-3f);
        lsu[tid] = s;
        ltu[tid] = be[tid] - mm * s;
    }
    __syncthreads();
    int r = tid >> 2, f = (tid & 3) * 4;
    bool mok = (m0 + r) < TT;
    const float* arow = Dc + (size_t)(mok ? (m0 + r) : 0) * QQ;
    const float* brow = yq + (size_t)(n0 + r) * QQ;
    float su = lsu[(n0 + r) % UU], tu = ltu[(n0 + r) % UU];
    int tg = tid >> 4, ug = tid & 15;
    float acc[4][4];
#pragma unroll
    for (int i = 0; i < 4; i++)
#pragma unroll
        for (int j = 0; j < 4; j++) acc[i][j] = 0.f;
    for (int kb = 0; kb < KC; kb += 32) {
        int kg = k0 + kb;
#pragma unroll
        for (int p = 0; p < 2; p++) {
            int ko = f + p * 16;
            float4 a4 = make_float4(0.f, 0.f, 0.f, 0.f);
            if (mok) a4 = *(const float4*)(arow + kg + ko);
            float4 b4 = *(const float4*)(brow + kg + ko);
#pragma unroll
            for (int i = 0; i < 4; i++) {
                float v = fmaf((&b4.x)[i], su, tu);
                lA[ko + i][r] = (&a4.x)[i];
                lB[ko + i][r] = (v > 0.f) ? v : 0.3f * v;
            }
        }
        __syncthreads();
#pragma unroll 2
        for (int kk = 0; kk < 32; kk++) {
            float4 a4 = *(const float4*)&lA[kk][tg * 4];
            float4 b4 = *(const float4*)&lB[kk][ug * 4];
#pragma unroll
            for (int i = 0; i < 4; i++) {
                float av = (&a4.x)[i];
                acc[i][0] = fmaf(av, b4.x, acc[i][0]);
                acc[i][1] = fmaf(av, b4.y, acc[i][1]);
                acc[i][2] = fmaf(av, b4.z, acc[i][2]);
                acc[i][3] = fmaf(av, b4.w, acc[i][3]);
            }
        }
        __syncthreads();
    }
    int n = n0 + ug * 4;
    int b = n / UU, u0 = n % UU;
#pragma unroll
    for (int i = 0; i < 4; i++) {
        int t = m0 + tg * 4 + i;
        if (t < TT)
            *(float4*)&part[(((size_t)qk * BB + b) * TT + t) * UU + u0] =
                make_float4(acc[i][0], acc[i][1], acc[i][2], acc[i][3]);
    }
}

// ---------------- redmix: grid (b, t-slice); reduce QKN partials + W-mix ----------------
template <int TT, int CC, int UU, int QKN, int TTp, int TS>
__global__ __launch_bounds__(256) void k_redmix(const float* __restrict__ part,
                                                const float* __restrict__ W,
                                                const float* __restrict__ bias,
                                                float* __restrict__ ym) {
    constexpr int TSL = TTp / TS;
    __shared__ float lyt[TSL][CC + 1];
    int b = blockIdx.x, ts = blockIdx.y, tid = threadIdx.x;
    int t0 = ts * TSL;
    for (int i = tid; i < TSL * CC; i += 256) {
        int tl = i / CC, c = i % CC;
        int t = t0 + tl;
        float v = 0.f;
        if (t < TT) {
#pragma unroll
            for (int k = 0; k < QKN; k++)
                v += part[(size_t)k * (BB * TT * CC) + ((size_t)b * TT + t) * CC + c];
        }
        lyt[tl][c] = v;
    }
    __syncthreads();
    for (int i = tid; i < UU * TSL; i += 256) {
        int u = i / TSL, tl = i % TSL;
        int t = t0 + tl;
        float m = 0.f;
        if (t < TT) {
            m = bias[u];
#pragma unroll
            for (int c = 0; c < CC; c++) m = fmaf(lyt[tl][c], W[c * UU + u], m);
        }
        ym[((size_t)b * UU + u) * TTp + t] = m;
    }
}

// ---------------- eval as tiled GEMM: yq[n=(b,u)][q] = sum_t ym[n][t]*Det[t][q], fused stats ----------------
template <int TT, int TTp, int UU>
__global__ __launch_bounds__(256) void k_evalG(const float* __restrict__ ym,
                                               const float* __restrict__ Det,
                                               float* __restrict__ yq,
                                               float* __restrict__ stats) {
    __shared__ float lA[32][68];
    __shared__ float lB[32][68];
    __shared__ float sred[2][64];
    int mt = blockIdx.x, qt = blockIdx.y, tid = threadIdx.x;
    int m0 = mt * 64, q0 = qt * 64;
    int r = tid >> 2, f = (tid & 3) * 4;
    const float* arow = ym + (size_t)(m0 + r) * TTp;
    int br = tid >> 4, bq = (tid & 15) * 4;
    int tg = tid >> 4, ug = tid & 15;
    float acc[4][4];
#pragma unroll
    for (int i = 0; i < 4; i++)
#pragma unroll
        for (int j = 0; j < 4; j++) acc[i][j] = 0.f;
    for (int kb = 0; kb < TT; kb += 32) {
#pragma unroll
        for (int p = 0; p < 2; p++) {
            int ko = f + p * 16;
            float4 a4 = *(const float4*)(arow + kb + ko);
#pragma unroll
            for (int i = 0; i < 4; i++) lA[ko + i][r] = (&a4.x)[i];
            int kk = br + p * 16;
            int t = kb + kk;
            float4 b4 = make_float4(0.f, 0.f, 0.f, 0.f);
            if (t < TT) b4 = *(const float4*)(Det + (size_t)t * QQ + q0 + bq);
            *(float4*)&lB[kk][bq] = b4;
        }
        __syncthreads();
#pragma unroll 2
        for (int kk = 0; kk < 32; kk++) {
            float4 a4 = *(const float4*)&lA[kk][tg * 4];
            float4 b4 = *(const float4*)&lB[kk][ug * 4];
#pragma unroll
            for (int i = 0; i < 4; i++) {
                float av = (&a4.x)[i];
                acc[i][0] = fmaf(av, b4.x, acc[i][0]);
                acc[i][1] = fmaf(av, b4.y, acc[i][1]);
                acc[i][2] = fmaf(av, b4.z, acc[i][2]);
                acc[i][3] = fmaf(av, b4.w, acc[i][3]);
            }
        }
        __syncthreads();
    }
    float s1[4], s2[4];
#pragma unroll
    for (int i = 0; i < 4; i++) {
        int m = m0 + tg * 4 + i;
        *(float4*)&yq[(size_t)m * QQ + q0 + ug * 4] =
            make_float4(acc[i][0], acc[i][1], acc[i][2], acc[i][3]);
        s1[i] = (acc[i][0] + acc[i][1]) + (acc[i][2] + acc[i][3]);
        s2[i] = fmaf(acc[i][0], acc[i][0], fmaf(acc[i][1], acc[i][1],
                 fmaf(acc[i][2], acc[i][2], acc[i][3] * acc[i][3])));
    }
#pragma unroll
    for (int o = 1; o < 16; o <<= 1) {
#pragma unroll
        for (int i = 0; i < 4; i++) {
            s1[i] += __shfl_xor(s1[i], o, 64);
            s2[i] += __shfl_xor(s2[i], o, 64);
        }
    }
    if (ug == 0) {
#pragma unroll
        for (int i = 0; i < 4; i++) {
            sred[0][tg * 4 + i] = s1[i];
            sred[1][tg * 4 + i] = s2[i];
        }
    }
    __syncthreads();
    if (tid < 2 * UU) {
        int which = tid / UU, u = tid % UU;
        float s = 0.f;
        for (int rr = u; rr < 64; rr += UU) s += sred[which][rr];
        atomicAdd(&stats[which * UU + u], s);
    }
}

// ---------------- norms: grid (b, blk), 4-way t-split, partial-reduce inline ----------------
__global__ __launch_bounds__(256) void k_norms(const float* __restrict__ part, float* __restrict__ ht0) {
    __shared__ float red[4][64];
    int b = blockIdx.x, blk = blockIdx.y;
    int tq = threadIdx.x >> 6, u = threadIdx.x & 63;
    const int offs[4] = {0, 1, 10, 35};
    const int ends[4] = {1, 10, 35, 84};
    float a = 0.f;
    for (int t = offs[blk] + tq; t < ends[blk]; t += 4) {
        float v = 0.f;
#pragma unroll
        for (int k = 0; k < QKN3; k++)
            v += part[(size_t)k * (BB * 84 * 64) + (b * 84 + t) * 64 + u];
        a = fmaf(v, v, a);
    }
    red[tq][u] = a;
    __syncthreads();
    if (tq == 0) {
        float s = red[0][u] + red[1][u] + red[2][u] + red[3][u];
        ht0[(blk * 64 + u) * BB + b] = sqrtf(fmaxf(s, 0.f));
    }
}

// ---------------- fc + batch-BN + relu: 8-way k-split, 4-acc unroll ----------------
template <int K, int J>
__global__ __launch_bounds__(512) void k_fc(const float* __restrict__ in, const float* __restrict__ W,
                                            const float* __restrict__ bias, const float* __restrict__ g,
                                            const float* __restrict__ be, float* __restrict__ out) {
    __shared__ float red[8][64];
    int j = blockIdx.x;
    int b = threadIdx.x & 63, kq = threadIdx.x >> 6;
    constexpr int KS = K / 8;
    int kbeg = kq * KS;
    float a0 = 0.f, a1 = 0.f, a2 = 0.f, a3 = 0.f;
#pragma unroll 4
    for (int k = kbeg; k < kbeg + KS; k += 4) {
        a0 = fmaf(in[k * BB + b], W[(size_t)k * J + j], a0);
        a1 = fmaf(in[(k + 1) * BB + b], W[(size_t)(k + 1) * J + j], a1);
        a2 = fmaf(in[(k + 2) * BB + b], W[(size_t)(k + 2) * J + j], a2);
        a3 = fmaf(in[(k + 3) * BB + b], W[(size_t)(k + 3) * J + j], a3);
    }
    red[kq][b] = (a0 + a1) + (a2 + a3);
    __syncthreads();
    if (kq == 0) {
        float acc = bias[j];
#pragma unroll
        for (int i = 0; i < 8; i++) acc += red[i][b];
        float s1 = acc, s2 = acc * acc;
#pragma unroll
        for (int o = 32; o > 0; o >>= 1) {
            s1 += __shfl_xor(s1, o, 64);
            s2 += __shfl_xor(s2, o, 64);
        }
        float m = s1 * (1.0f / 64.f);
        float var = s2 * (1.0f / 64.f) - m * m;
        float sc = g[j] * rsqrtf(fmaxf(var, 0.f) + 1e-3f);
        float v = (acc - m) * sc + be[j];
        out[j * BB + b] = fmaxf(v, 0.f);
    }
}

// ---------------- output layer + softmax ----------------
__global__ __launch_bounds__(256) void k_out(const float* __restrict__ ht2, const float* __restrict__ Wout,
                                             const float* __restrict__ bout, float* __restrict__ outp) {
    __shared__ float red[4][64];
    __shared__ float sm[64];
    int b = blockIdx.x;
    int o = threadIdx.x & 63, kq = threadIdx.x >> 6;
    float a0 = 0.f, a1 = 0.f, a2 = 0.f, a3 = 0.f;
    int kbeg = kq * 64;
    if (o < 40) {
#pragma unroll 4
        for (int k = kbeg; k < kbeg + 64; k += 4) {
            a0 = fmaf(ht2[k * BB + b], Wout[k * 40 + o], a0);
            a1 = fmaf(ht2[(k + 1) * BB + b], Wout[(k + 1) * 40 + o], a1);
            a2 = fmaf(ht2[(k + 2) * BB + b], Wout[(k + 2) * 40 + o], a2);
            a3 = fmaf(ht2[(k + 3) * BB + b], Wout[(k + 3) * 40 + o], a3);
        }
    }
    red[kq][o] = (a0 + a1) + (a2 + a3);
    __syncthreads();
    if (kq == 0) {
        float acc = red[0][o] + red[1][o] + red[2][o] + red[3][o] + ((o < 40) ? bout[o] : 0.f);
        sm[o] = (o < 40) ? acc : -3.0e38f;
        __syncthreads();
        for (int s = 32; s > 0; s >>= 1) {
            if (o < s) sm[o] = fmaxf(sm[o], sm[o + s]);
            __syncthreads();
        }
        float m = sm[0];
        __syncthreads();
        const float L2E = 1.4426950408889634f;
        float e = (o < 40) ? exp2f((acc - m) * L2E) : 0.f;
        sm[o] = e;
        __syncthreads();
        for (int s = 32; s > 0; s >>= 1) {
            if (o < s) sm[o] += sm[o + s];
            __syncthreads();
        }
        if (o < 40) outp[b * 40 + o] = e / sm[0];
    }
}

// ---------------- workspace layout (float offsets, no aliasing; ws is ~268 MB) ----------------
#define OFF_PBUF 0           // 1572864
#define OFF_DG0T 1572864     // 36864
#define OFF_RS0 1609728      // 1024
#define OFF_DET1 1610752     // 168960
#define OFF_DET2 1779712     // 86016
#define OFF_YQ 1865728       // 4194304
#define OFF_YM 6060032       // 393216
#define OFF_LSH 6453248      // 13824
#define OFF_HT0 6467072      // 16384
#define OFF_HT1 6483456      // 32768
#define OFF_HT2 6516224      // 16384
#define OFF_STATS 6532608    // 224
#define OFF_PART 6532864     // 8*172032 = 1376256 (coef1/coef2)
#define OFF_PART3 7909120    // 8*344064 = 2752512 (coef3)

extern "C" void kernel_launch(void* const* d_in, const int* in_sizes, int n_in,
                              void* d_out, int out_size, void* d_ws, size_t ws_size,
                              hipStream_t stream) {
    const float* x = (const float*)d_in[0];
    const float* shell_dirs = (const float*)d_in[1];
    const float* A_sh = (const float*)d_in[2];
    const float* D_eval0 = (const float*)d_in[3];
    const float* D_eval1 = (const float*)d_in[4];
    const float* D_eval2 = (const float*)d_in[5];
    const float* D_coef1 = (const float*)d_in[6];
    const float* D_coef2 = (const float*)d_in[7];
    const float* D_coef_last = (const float*)d_in[8];
    const float* W0 = (const float*)d_in[9];
    const float* b0 = (const float*)d_in[10];
    const float* W1 = (const float*)d_in[11];
    const float* b1 = (const float*)d_in[12];
    const float* W2 = (const float*)d_in[13];
    const float* b2 = (const float*)d_in[14];
    const float* g0 = (const float*)d_in[15];
    const float* be0 = (const float*)d_in[16];
    const float* g1 = (const float*)d_in[17];
    const float* be1 = (const float*)d_in[18];
    const float* g2 = (const float*)d_in[19];
    const float* be2 = (const float*)d_in[20];
    const float* Wfc1 = (const float*)d_in[21];
    const float* bfc1 = (const float*)d_in[22];
    const float* gfc1 = (const float*)d_in[23];
    const float* befc1 = (const float*)d_in[24];
    const float* Wfc2 = (const float*)d_in[25];
    const float* bfc2 = (const float*)d_in[26];
    const float* gfc2 = (const float*)d_in[27];
    const float* befc2 = (const float*)d_in[28];
    const float* Wout = (const float*)d_in[29];
    const float* bout = (const float*)d_in[30];
    float* out = (float*)d_out;

    float* ws = (float*)d_ws;
    float* pbuf = ws + OFF_PBUF;
    float* Dg0t = ws + OFF_DG0T;
    float* rs0 = ws + OFF_RS0;
    float* Det1 = ws + OFF_DET1;
    float* Det2 = ws + OFF_DET2;
    float* yq = ws + OFF_YQ;
    float* ym = ws + OFF_YM;
    float* lshp = ws + OFF_LSH;
    float* ht0 = ws + OFF_HT0;
    float* ht1 = ws + OFF_HT1;
    float* ht2 = ws + OFF_HT2;
    float* stats = ws + OFF_STATS;
    float* part = ws + OFF_PART;
    float* part3 = ws + OFF_PART3;
    float* stats0 = stats;
    float* stats1 = stats + 32;
    float* stats2 = stats + 96;

    k_preshell<<<PREPB + BB * NCH, 256, 0, stream>>>(
        D_eval0, D_eval1, D_eval2, Dg0t, rs0, Det1, Det2, stats, x, shell_dirs, pbuf);
    k_sh<<<dim3(BB, 3, 2), 256, 0, stream>>>(pbuf, A_sh, lshp);
    k_eval0<<<dim3(4, BB), 256, 0, stream>>>(lshp, W0, b0, Dg0t, rs0, yq, stats0);
    k_coefG<165, 16, 8><<<dim3(3, 16, 8), 256, 0, stream>>>(yq, D_coef1, stats0, g0, be0, part);
    k_redmix<165, 16, 32, 8, 192, 8><<<dim3(BB, 8), 256, 0, stream>>>(part, W1, b1, ym);
    k_evalG<165, 192, 32><<<dim3(32, 16), 256, 0, stream>>>(ym, Det1, yq, stats1);
    k_coefG<84, 32, 8><<<dim3(2, 32, 8), 256, 0, stream>>>(yq, D_coef2, stats1, g1, be1, part);
    k_redmix<84, 32, 64, 8, 96, 8><<<dim3(BB, 8), 256, 0, stream>>>(part, W2, b2, ym);
    k_evalG<84, 96, 64><<<dim3(64, 16), 256, 0, stream>>>(ym, Det2, yq, stats2);
    k_coefG<84, 64, QKN3><<<dim3(2, 64, QKN3), 256, 0, stream>>>(yq, D_coef_last, stats2, g2, be2, part3);
    k_norms<<<dim3(BB, 4), 256, 0, stream>>>(part3, ht0);
    k_fc<256, 512><<<512, 512, 0, stream>>>(ht0, Wfc1, bfc1, gfc1, befc1, ht1);
    k_fc<512, 256><<<256, 512, 0, stream>>>(ht1, Wfc2, bfc2, gfc2, befc2, ht2);
    k_out<<<BB, 256, 0, stream>>>(ht2, Wout, bout, out);
}